// Round 7
// baseline (444.359 us; speedup 1.0000x reference)
//
#include <hip/hip_runtime.h>

#define HID   256
#define BATCH 8
#define TT    256   // time steps (SEQ-1)
#define SEQL  257
#define VOCAB 29
#define EMB   64
#define TG    4     // attn t-tile
#define CS    32    // pipeline chunk size
#define NCH   (TT / CS)

typedef _Float16 f16;
typedef f16  f16x8 __attribute__((ext_vector_type(8)));
typedef float f32x4 __attribute__((ext_vector_type(4)));

__device__ __forceinline__ float fast_tanh(float x) {
    float e = exp2f(x * 2.8853900817779268f);
    return 1.0f - 2.0f * __builtin_amdgcn_rcpf(1.0f + e);
}

// C0[t][b][i] = emb[x[b][t]] . W_ih0[i] + b_ih0[i] + b_hh0[i]
__global__ __launch_bounds__(256) void pre0_kernel(
    const int* __restrict__ x, const float* __restrict__ embed,
    const float* __restrict__ Wih0, const float* __restrict__ bih0,
    const float* __restrict__ bhh0, float* __restrict__ C0)
{
    int b  = blockIdx.x & 7;
    int t0 = (blockIdx.x >> 3) * 8;
    int tid = threadIdx.x;
    __shared__ float er[8][EMB];
    for (int idx = tid; idx < 8 * EMB; idx += 256) {
        int tt = idx >> 6, j = idx & 63;
        er[tt][j] = embed[x[b * SEQL + t0 + tt] * EMB + j];
    }
    __syncthreads();
    int i = tid;
    float base = bih0[i] + bhh0[i];
    float acc[8];
#pragma unroll
    for (int tt = 0; tt < 8; ++tt) acc[tt] = base;
    const float* wr = Wih0 + i * EMB;
    for (int j = 0; j < EMB; j += 4) {
        float4 w = *(const float4*)&wr[j];
#pragma unroll
        for (int tt = 0; tt < 8; ++tt) {
            float4 h = *(const float4*)&er[tt][j];
            acc[tt] += h.x * w.x + h.y * w.y + h.z * w.z + h.w * w.w;
        }
    }
#pragma unroll
    for (int tt = 0; tt < 8; ++tt)
        C0[((t0 + tt) * BATCH + b) * HID + i] = acc[tt];
}

// Chunked 2-layer pipeline. Launch j (j=0..NCH), 16 blocks:
//   blocks 0-7 : layer0, batch=blk,   steps [j*CS, (j+1)*CS)      (skip j==NCH)
//   blocks 8-15: layer1, batch=blk-8, steps [(j-1)*CS, j*CS)      (skip j==0)
// Layer1 reads the h0 chunk layer0 wrote in the PREVIOUS launch (stream order).
__global__ __launch_bounds__(512) void recpipe_kernel(
    const float* __restrict__ Whh0, const float* __restrict__ Wih1,
    const float* __restrict__ Whh1, const float* __restrict__ bih1,
    const float* __restrict__ bhh1, const float* __restrict__ C0,
    float* __restrict__ H0, float* __restrict__ Hs, int chunk)
{
    __shared__ f16 hb[2][HID];      // recurrent state (h0 or h1)
    __shared__ f16 hs0[CS][HID];    // layer1: staged h0 chunk
    int tid = threadIdx.x;
    int wave = tid >> 6, lane = tid & 63;
    int lrow = lane & 15, lkg = lane >> 4;
    int i0 = wave * 32 + lrow, i1 = i0 + 16;
    const f32x4 Z = {0.f, 0.f, 0.f, 0.f};

    // Persistent A-fragments: zero once; masked ds_read touches only lrow==0 lanes.
    f16x8 a[8];
#pragma unroll
    for (int kt = 0; kt < 8; ++kt)
#pragma unroll
        for (int e = 0; e < 8; ++e) a[kt][e] = (f16)0.f;

    if (blockIdx.x < 8) {
        // ---------------- layer 0 ----------------
        if (chunk == NCH) return;
        int b = blockIdx.x;
        int tbase = chunk * CS;
        // B-frag (verified layout): lane holds B[k=kt*32+lkg*8+e][n=wave*32+ct*16+lrow] = W[n][k]
        f16x8 bf[8][2];
#pragma unroll
        for (int kt = 0; kt < 8; ++kt)
#pragma unroll
            for (int ct = 0; ct < 2; ++ct) {
                int n = wave * 32 + ct * 16 + lrow;
                const float* src = Whh0 + n * HID + kt * 32 + lkg * 8;
                f16x8 v;
#pragma unroll
                for (int e = 0; e < 8; ++e) v[e] = (f16)src[e];
                bf[kt][ct] = v;
            }
        if (tid < HID)
            hb[0][tid] = (chunk == 0) ? (f16)0.f
                       : (f16)H0[((size_t)b * TT + tbase - 1) * HID + tid];
        __syncthreads();

        const float* cp = C0 + b * HID;
        float c0 = cp[(size_t)tbase * BATCH * HID + i0];
        float c1 = cp[(size_t)tbase * BATCH * HID + i1];
        float* ho = H0 + ((size_t)b * TT + tbase) * HID;

#define ASTEP(CUR, NXT, T)                                                          \
    {                                                                               \
        int tn = ((T) + 1 < TT) ? (T) + 1 : TT - 1;                                 \
        float cn0 = cp[(size_t)tn * BATCH * HID + i0];                              \
        float cn1 = cp[(size_t)tn * BATCH * HID + i1];                              \
        if (lrow == 0) {                                                            \
            _Pragma("unroll")                                                       \
            for (int kt = 0; kt < 8; ++kt)                                          \
                a[kt] = *(const f16x8*)&hb[CUR][kt * 32 + lkg * 8];                 \
        }                                                                           \
        f32x4 p00 = __builtin_amdgcn_mfma_f32_16x16x32_f16(a[0], bf[0][0], Z, 0, 0, 0); \
        f32x4 p01 = __builtin_amdgcn_mfma_f32_16x16x32_f16(a[0], bf[0][1], Z, 0, 0, 0); \
        f32x4 p10 = __builtin_amdgcn_mfma_f32_16x16x32_f16(a[2], bf[2][0], Z, 0, 0, 0); \
        f32x4 p11 = __builtin_amdgcn_mfma_f32_16x16x32_f16(a[2], bf[2][1], Z, 0, 0, 0); \
        f32x4 p20 = __builtin_amdgcn_mfma_f32_16x16x32_f16(a[4], bf[4][0], Z, 0, 0, 0); \
        f32x4 p21 = __builtin_amdgcn_mfma_f32_16x16x32_f16(a[4], bf[4][1], Z, 0, 0, 0); \
        f32x4 p30 = __builtin_amdgcn_mfma_f32_16x16x32_f16(a[6], bf[6][0], Z, 0, 0, 0); \
        f32x4 p31 = __builtin_amdgcn_mfma_f32_16x16x32_f16(a[6], bf[6][1], Z, 0, 0, 0); \
        p00 = __builtin_amdgcn_mfma_f32_16x16x32_f16(a[1], bf[1][0], p00, 0, 0, 0); \
        p01 = __builtin_amdgcn_mfma_f32_16x16x32_f16(a[1], bf[1][1], p01, 0, 0, 0); \
        p10 = __builtin_amdgcn_mfma_f32_16x16x32_f16(a[3], bf[3][0], p10, 0, 0, 0); \
        p11 = __builtin_amdgcn_mfma_f32_16x16x32_f16(a[3], bf[3][1], p11, 0, 0, 0); \
        p20 = __builtin_amdgcn_mfma_f32_16x16x32_f16(a[5], bf[5][0], p20, 0, 0, 0); \
        p21 = __builtin_amdgcn_mfma_f32_16x16x32_f16(a[5], bf[5][1], p21, 0, 0, 0); \
        p30 = __builtin_amdgcn_mfma_f32_16x16x32_f16(a[7], bf[7][0], p30, 0, 0, 0); \
        p31 = __builtin_amdgcn_mfma_f32_16x16x32_f16(a[7], bf[7][1], p31, 0, 0, 0); \
        float v0 = fast_tanh(((p00[0] + p10[0]) + (p20[0] + p30[0])) + c0);         \
        float v1 = fast_tanh(((p01[0] + p11[0]) + (p21[0] + p31[0])) + c1);         \
        if (lane < 16) {                                                            \
            hb[NXT][i0] = (f16)v0;                                                  \
            hb[NXT][i1] = (f16)v1;                                                  \
            ho[i0] = v0;                                                            \
            ho[i1] = v1;                                                            \
        }                                                                           \
        ho += HID;                                                                  \
        c0 = cn0; c1 = cn1;                                                         \
        asm volatile("s_waitcnt lgkmcnt(0)\n\ts_barrier" ::: "memory");             \
    }

        for (int lt = 0; lt < CS; lt += 2) {
            ASTEP(0, 1, tbase + lt)
            ASTEP(1, 0, tbase + lt + 1)
        }
#undef ASTEP
    } else {
        // ---------------- layer 1 ----------------
        if (chunk == 0) return;
        int b = blockIdx.x - 8;
        int tbase = (chunk - 1) * CS;
        f16x8 bfI[8][2], bfH[8][2];
#pragma unroll
        for (int kt = 0; kt < 8; ++kt)
#pragma unroll
            for (int ct = 0; ct < 2; ++ct) {
                int n = wave * 32 + ct * 16 + lrow;
                const float* sI = Wih1 + n * HID + kt * 32 + lkg * 8;
                const float* sH = Whh1 + n * HID + kt * 32 + lkg * 8;
                f16x8 vI, vH;
#pragma unroll
                for (int e = 0; e < 8; ++e) { vI[e] = (f16)sI[e]; vH[e] = (f16)sH[e]; }
                bfI[kt][ct] = vI; bfH[kt][ct] = vH;
            }
        float bs0 = bih1[i0] + bhh1[i0];
        float bs1 = bih1[i1] + bhh1[i1];
        // stage this chunk's h0 (written by layer0 in the previous launch)
        for (int idx = tid; idx < CS * HID; idx += 512) {
            int lt = idx >> 8, i = idx & 255;
            hs0[lt][i] = (f16)H0[((size_t)b * TT + tbase + lt) * HID + i];
        }
        if (tid < HID)
            hb[0][tid] = (chunk == 1) ? (f16)0.f
                       : (f16)Hs[((size_t)b * TT + tbase - 1) * HID + tid];
        __syncthreads();

        float* hp = Hs + ((size_t)b * TT + tbase) * HID;

#define BSTEP(CUR, NXT, LT)                                                         \
    {                                                                               \
        if (lrow == 0) {                                                            \
            _Pragma("unroll")                                                       \
            for (int kt = 0; kt < 8; ++kt)                                          \
                a[kt] = *(const f16x8*)&hs0[LT][kt * 32 + lkg * 8];                 \
        }                                                                           \
        f32x4 p00 = __builtin_amdgcn_mfma_f32_16x16x32_f16(a[0], bfI[0][0], Z, 0, 0, 0); \
        f32x4 p01 = __builtin_amdgcn_mfma_f32_16x16x32_f16(a[0], bfI[0][1], Z, 0, 0, 0); \
        f32x4 p10 = __builtin_amdgcn_mfma_f32_16x16x32_f16(a[2], bfI[2][0], Z, 0, 0, 0); \
        f32x4 p11 = __builtin_amdgcn_mfma_f32_16x16x32_f16(a[2], bfI[2][1], Z, 0, 0, 0); \
        f32x4 p20 = __builtin_amdgcn_mfma_f32_16x16x32_f16(a[4], bfI[4][0], Z, 0, 0, 0); \
        f32x4 p21 = __builtin_amdgcn_mfma_f32_16x16x32_f16(a[4], bfI[4][1], Z, 0, 0, 0); \
        f32x4 p30 = __builtin_amdgcn_mfma_f32_16x16x32_f16(a[6], bfI[6][0], Z, 0, 0, 0); \
        f32x4 p31 = __builtin_amdgcn_mfma_f32_16x16x32_f16(a[6], bfI[6][1], Z, 0, 0, 0); \
        p00 = __builtin_amdgcn_mfma_f32_16x16x32_f16(a[1], bfI[1][0], p00, 0, 0, 0); \
        p01 = __builtin_amdgcn_mfma_f32_16x16x32_f16(a[1], bfI[1][1], p01, 0, 0, 0); \
        p10 = __builtin_amdgcn_mfma_f32_16x16x32_f16(a[3], bfI[3][0], p10, 0, 0, 0); \
        p11 = __builtin_amdgcn_mfma_f32_16x16x32_f16(a[3], bfI[3][1], p11, 0, 0, 0); \
        p20 = __builtin_amdgcn_mfma_f32_16x16x32_f16(a[5], bfI[5][0], p20, 0, 0, 0); \
        p21 = __builtin_amdgcn_mfma_f32_16x16x32_f16(a[5], bfI[5][1], p21, 0, 0, 0); \
        p30 = __builtin_amdgcn_mfma_f32_16x16x32_f16(a[7], bfI[7][0], p30, 0, 0, 0); \
        p31 = __builtin_amdgcn_mfma_f32_16x16x32_f16(a[7], bfI[7][1], p31, 0, 0, 0); \
        if (lrow == 0) {                                                            \
            _Pragma("unroll")                                                       \
            for (int kt = 0; kt < 8; ++kt)                                          \
                a[kt] = *(const f16x8*)&hb[CUR][kt * 32 + lkg * 8];                 \
        }                                                                           \
        p00 = __builtin_amdgcn_mfma_f32_16x16x32_f16(a[0], bfH[0][0], p00, 0, 0, 0); \
        p01 = __builtin_amdgcn_mfma_f32_16x16x32_f16(a[0], bfH[0][1], p01, 0, 0, 0); \
        p10 = __builtin_amdgcn_mfma_f32_16x16x32_f16(a[2], bfH[2][0], p10, 0, 0, 0); \
        p11 = __builtin_amdgcn_mfma_f32_16x16x32_f16(a[2], bfH[2][1], p11, 0, 0, 0); \
        p20 = __builtin_amdgcn_mfma_f32_16x16x32_f16(a[4], bfH[4][0], p20, 0, 0, 0); \
        p21 = __builtin_amdgcn_mfma_f32_16x16x32_f16(a[4], bfH[4][1], p21, 0, 0, 0); \
        p30 = __builtin_amdgcn_mfma_f32_16x16x32_f16(a[6], bfH[6][0], p30, 0, 0, 0); \
        p31 = __builtin_amdgcn_mfma_f32_16x16x32_f16(a[6], bfH[6][1], p31, 0, 0, 0); \
        p00 = __builtin_amdgcn_mfma_f32_16x16x32_f16(a[1], bfH[1][0], p00, 0, 0, 0); \
        p01 = __builtin_amdgcn_mfma_f32_16x16x32_f16(a[1], bfH[1][1], p01, 0, 0, 0); \
        p10 = __builtin_amdgcn_mfma_f32_16x16x32_f16(a[3], bfH[3][0], p10, 0, 0, 0); \
        p11 = __builtin_amdgcn_mfma_f32_16x16x32_f16(a[3], bfH[3][1], p11, 0, 0, 0); \
        p20 = __builtin_amdgcn_mfma_f32_16x16x32_f16(a[5], bfH[5][0], p20, 0, 0, 0); \
        p21 = __builtin_amdgcn_mfma_f32_16x16x32_f16(a[5], bfH[5][1], p21, 0, 0, 0); \
        p30 = __builtin_amdgcn_mfma_f32_16x16x32_f16(a[7], bfH[7][0], p30, 0, 0, 0); \
        p31 = __builtin_amdgcn_mfma_f32_16x16x32_f16(a[7], bfH[7][1], p31, 0, 0, 0); \
        float v0 = fast_tanh(((p00[0] + p10[0]) + (p20[0] + p30[0])) + bs0);        \
        float v1 = fast_tanh(((p01[0] + p11[0]) + (p21[0] + p31[0])) + bs1);        \
        if (lane < 16) {                                                            \
            hb[NXT][i0] = (f16)v0;                                                  \
            hb[NXT][i1] = (f16)v1;                                                  \
            hp[i0] = v0;                                                            \
            hp[i1] = v1;                                                            \
        }                                                                           \
        hp += HID;                                                                  \
        asm volatile("s_waitcnt lgkmcnt(0)\n\ts_barrier" ::: "memory");             \
    }

        for (int lt = 0; lt < CS; lt += 2) {
            BSTEP(0, 1, lt)
            BSTEP(1, 0, lt + 1)
        }
#undef BSTEP
    }
}

// tq[b][t][i] = tanh(Hs@Wq^T), tkT[b][i][t] = tanh(Hs@Wk^T) (transposed for coalesced attn reads)
__global__ __launch_bounds__(256) void gemmqk_kernel(
    const float* __restrict__ In, const float* __restrict__ Wq,
    const float* __restrict__ Wk, float* __restrict__ Oq, float* __restrict__ OkT)
{
    int b  = blockIdx.x & 7;
    int t0 = (blockIdx.x >> 3) * 8;
    int tid = threadIdx.x;
    __shared__ float hs[8][HID];
    for (int idx = tid; idx < 8 * HID; idx += 256) {
        int tt = idx >> 8, j = idx & 255;
        hs[tt][j] = In[((size_t)b * TT + t0 + tt) * HID + j];
    }
    __syncthreads();
    int i = tid;
    float aq[8], ak[8];
#pragma unroll
    for (int tt = 0; tt < 8; ++tt) { aq[tt] = 0.f; ak[tt] = 0.f; }
    const float* wq = Wq + i * HID;
    const float* wk = Wk + i * HID;
    for (int j = 0; j < HID; j += 4) {
        float4 q = *(const float4*)&wq[j];
        float4 k = *(const float4*)&wk[j];
#pragma unroll
        for (int tt = 0; tt < 8; ++tt) {
            float4 h = *(const float4*)&hs[tt][j];
            aq[tt] += h.x * q.x + h.y * q.y + h.z * q.z + h.w * q.w;
            ak[tt] += h.x * k.x + h.y * k.y + h.z * k.z + h.w * k.w;
        }
    }
#pragma unroll
    for (int tt = 0; tt < 8; ++tt)
        Oq[((size_t)b * TT + t0 + tt) * HID + i] = fast_tanh(aq[tt]);
    float4 kv0 = { fast_tanh(ak[0]), fast_tanh(ak[1]), fast_tanh(ak[2]), fast_tanh(ak[3]) };
    float4 kv1 = { fast_tanh(ak[4]), fast_tanh(ak[5]), fast_tanh(ak[6]), fast_tanh(ak[7]) };
    float* ko = OkT + ((size_t)b * HID + i) * TT + t0;
    *(float4*)&ko[0] = kv0;
    *(float4*)&ko[4] = kv1;
}

// Per (b, t-tile of TG): scores via tanh addition identity:
// tanh(q+k) = (tq+tk)/(1+tq*tk). tkT is [b][j][s] -> coalesced loads over s=tid.
__global__ __launch_bounds__(256) void attn_kernel(
    const float* __restrict__ tq, const float* __restrict__ tkT,
    const float* __restrict__ vvec, const float* __restrict__ Hs,
    const float* __restrict__ Wfc, const float* __restrict__ bfc,
    float* __restrict__ out)
{
    int b  = blockIdx.x >> 6;
    int t0 = (blockIdx.x & 63) * TG;
    int tid = threadIdx.x;
    int wave = tid >> 6, lane = tid & 63;
    __shared__ float qs[TG][HID], vs[HID], alpha[TG][HID], cvec[TG][2 * HID];
    __shared__ float redm[4][TG], reds[4][TG];
#pragma unroll
    for (int j = 0; j < TG; ++j)
        qs[j][tid] = tq[((size_t)b * TT + t0 + j) * HID + tid];
    vs[tid] = vvec[tid];
    __syncthreads();

    float sc[TG];
#pragma unroll
    for (int j = 0; j < TG; ++j) sc[j] = -1e30f;
    if ((wave << 6) < t0 + TG) {   // causality: whole-wave skip for s >= t0+TG
        const float* kT = tkT + (size_t)b * HID * TT + tid;
        float a0 = 0.f, a1 = 0.f, a2 = 0.f, a3 = 0.f;
        for (int jj = 0; jj < HID; jj += 4) {
            float k0 = kT[(size_t)(jj + 0) * TT];
            float k1 = kT[(size_t)(jj + 1) * TT];
            float k2 = kT[(size_t)(jj + 2) * TT];
            float k3 = kT[(size_t)(jj + 3) * TT];
            float4 vv = *(const float4*)&vs[jj];
            float4 q0 = *(const float4*)&qs[0][jj];
            float4 q1 = *(const float4*)&qs[1][jj];
            float4 q2 = *(const float4*)&qs[2][jj];
            float4 q3 = *(const float4*)&qs[3][jj];
#define TADD(qc, kc, vc, acc) { float num = qc + kc; float den = __builtin_fmaf(qc, kc, 1.f); acc += vc * num * __builtin_amdgcn_rcpf(den); }
            TADD(q0.x, k0, vv.x, a0) TADD(q0.y, k1, vv.y, a0) TADD(q0.z, k2, vv.z, a0) TADD(q0.w, k3, vv.w, a0)
            TADD(q1.x, k0, vv.x, a1) TADD(q1.y, k1, vv.y, a1) TADD(q1.z, k2, vv.z, a1) TADD(q1.w, k3, vv.w, a1)
            TADD(q2.x, k0, vv.x, a2) TADD(q2.y, k1, vv.y, a2) TADD(q2.z, k2, vv.z, a2) TADD(q2.w, k3, vv.w, a2)
            TADD(q3.x, k0, vv.x, a3) TADD(q3.y, k1, vv.y, a3) TADD(q3.z, k2, vv.z, a3) TADD(q3.w, k3, vv.w, a3)
#undef TADD
        }
        if (tid < t0 + 0) sc[0] = a0;
        if (tid < t0 + 1) sc[1] = a1;
        if (tid < t0 + 2) sc[2] = a2;
        if (tid < t0 + 3) sc[3] = a3;
    }
    float m0 = sc[0], m1 = sc[1], m2 = sc[2], m3 = sc[3];
#pragma unroll
    for (int off = 32; off; off >>= 1) {
        m0 = fmaxf(m0, __shfl_down(m0, off));
        m1 = fmaxf(m1, __shfl_down(m1, off));
        m2 = fmaxf(m2, __shfl_down(m2, off));
        m3 = fmaxf(m3, __shfl_down(m3, off));
    }
    if (lane == 0) { redm[wave][0] = m0; redm[wave][1] = m1; redm[wave][2] = m2; redm[wave][3] = m3; }
    __syncthreads();
    float ej[TG];
#pragma unroll
    for (int j = 0; j < TG; ++j) {
        float m = fmaxf(fmaxf(redm[0][j], redm[1][j]), fmaxf(redm[2][j], redm[3][j]));
        ej[j] = (tid < t0 + j) ? exp2f((sc[j] - m) * 1.4426950408889634f) : 0.f;
    }
    float z0 = ej[0], z1 = ej[1], z2 = ej[2], z3 = ej[3];
#pragma unroll
    for (int off = 32; off; off >>= 1) {
        z0 += __shfl_down(z0, off);
        z1 += __shfl_down(z1, off);
        z2 += __shfl_down(z2, off);
        z3 += __shfl_down(z3, off);
    }
    if (lane == 0) { reds[wave][0] = z0; reds[wave][1] = z1; reds[wave][2] = z2; reds[wave][3] = z3; }
    __syncthreads();
#pragma unroll
    for (int j = 0; j < TG; ++j) {
        float z = reds[0][j] + reds[1][j] + reds[2][j] + reds[3][j];
        alpha[j][tid] = (t0 + j == 0) ? 0.f : ej[j] * __builtin_amdgcn_rcpf(z);
    }
    __syncthreads();

    float c0 = 0.f, c1 = 0.f, c2 = 0.f, c3 = 0.f;
    const float* hb = Hs + (size_t)b * TT * HID;
    for (int s = 0; s < t0 + TG; s += 4) {
        float4 av0 = *(const float4*)&alpha[0][s];
        float4 av1 = *(const float4*)&alpha[1][s];
        float4 av2 = *(const float4*)&alpha[2][s];
        float4 av3 = *(const float4*)&alpha[3][s];
        float h0 = hb[(s + 0) * HID + tid];
        float h1 = hb[(s + 1) * HID + tid];
        float h2 = hb[(s + 2) * HID + tid];
        float h3 = hb[(s + 3) * HID + tid];
        c0 += av0.x * h0 + av0.y * h1 + av0.z * h2 + av0.w * h3;
        c1 += av1.x * h0 + av1.y * h1 + av1.z * h2 + av1.w * h3;
        c2 += av2.x * h0 + av2.y * h1 + av2.z * h2 + av2.w * h3;
        c3 += av3.x * h0 + av3.y * h1 + av3.z * h2 + av3.w * h3;
    }
    cvec[0][tid] = hb[(size_t)(t0 + 0) * HID + tid]; cvec[0][HID + tid] = c0;
    cvec[1][tid] = hb[(size_t)(t0 + 1) * HID + tid]; cvec[1][HID + tid] = c1;
    cvec[2][tid] = hb[(size_t)(t0 + 2) * HID + tid]; cvec[2][HID + tid] = c2;
    cvec[3][tid] = hb[(size_t)(t0 + 3) * HID + tid]; cvec[3][HID + tid] = c3;
    __syncthreads();

    if (tid < VOCAB * 8) {
        int o = tid >> 3, p = tid & 7;
        const float* wr = Wfc + o * 2 * HID + p * 64;
#pragma unroll
        for (int j = 0; j < TG; ++j) {
            const float* cv = &cvec[j][p * 64];
            float a = 0.f;
            for (int jj = 0; jj < 64; jj += 4) {
                float4 w  = *(const float4*)&wr[jj];
                float4 cc = *(const float4*)&cv[jj];
                a += w.x * cc.x + w.y * cc.y + w.z * cc.z + w.w * cc.w;
            }
            a += __shfl_down(a, 4);
            a += __shfl_down(a, 2);
            a += __shfl_down(a, 1);
            if (p == 0) out[((size_t)b * TT + t0 + j) * VOCAB + o] = a + bfc[o];
        }
    }
}

extern "C" void kernel_launch(void* const* d_in, const int* in_sizes, int n_in,
                              void* d_out, int out_size, void* d_ws, size_t ws_size,
                              hipStream_t stream)
{
    (void)in_sizes; (void)n_in; (void)out_size; (void)ws_size;
    const int*   x     = (const int*)d_in[0];
    const float* embed = (const float*)d_in[1];
    const float* Wih0  = (const float*)d_in[2];
    const float* bih0  = (const float*)d_in[3];
    const float* Whh0  = (const float*)d_in[4];
    const float* bhh0  = (const float*)d_in[5];
    const float* Wih1  = (const float*)d_in[6];
    const float* bih1  = (const float*)d_in[7];
    const float* Whh1  = (const float*)d_in[8];
    const float* bhh1  = (const float*)d_in[9];
    const float* Wq    = (const float*)d_in[10];
    const float* Wk    = (const float*)d_in[11];
    const float* vvec  = (const float*)d_in[12];
    const float* Wfc   = (const float*)d_in[13];
    const float* bfc   = (const float*)d_in[14];
    float* out = (float*)d_out;
    float* ws  = (float*)d_ws;

    const size_t SZ = (size_t)TT * BATCH * HID;  // 524288 floats = 2 MB
    float* C0  = ws;
    float* H0  = ws + SZ;      // h0 history, reused as tq
    float* Hs  = ws + 2 * SZ;
    float* tkT = ws + 3 * SZ;

    pre0_kernel<<<256, 256, 0, stream>>>(x, embed, Wih0, bih0, bhh0, C0);
    for (int j = 0; j <= NCH; ++j)
        recpipe_kernel<<<16, 512, 0, stream>>>(Whh0, Wih1, Whh1, bih1, bhh1, C0, H0, Hs, j);
    gemmqk_kernel<<<256, 256, 0, stream>>>(Hs, Wq, Wk, H0, tkT);
    attn_kernel<<<512, 256, 0, stream>>>(H0, tkT, vvec, Hs, Wfc, bfc, out);
}

// Round 8
// 346.401 us; speedup vs baseline: 1.2828x; 1.2828x over previous
//
#include <hip/hip_runtime.h>

#define HID   256
#define BATCH 8
#define TT    256   // time steps (SEQ-1)
#define SEQL  257
#define VOCAB 29
#define EMB   64
#define TG    4     // attn t-tile

typedef _Float16 f16;
typedef f16  f16x8 __attribute__((ext_vector_type(8)));
typedef float f32x4 __attribute__((ext_vector_type(4)));

__device__ __forceinline__ float fast_tanh(float x) {
    float e = exp2f(x * 2.8853900817779268f);
    return 1.0f - 2.0f * __builtin_amdgcn_rcpf(1.0f + e);
}

// C0[t][b][i] = emb[x[b][t]] . W_ih0[i] + b_ih0[i] + b_hh0[i]
__global__ __launch_bounds__(256) void pre0_kernel(
    const int* __restrict__ x, const float* __restrict__ embed,
    const float* __restrict__ Wih0, const float* __restrict__ bih0,
    const float* __restrict__ bhh0, float* __restrict__ C0)
{
    int b  = blockIdx.x & 7;
    int t0 = (blockIdx.x >> 3) * 8;
    int tid = threadIdx.x;
    __shared__ float er[8][EMB];
    for (int idx = tid; idx < 8 * EMB; idx += 256) {
        int tt = idx >> 6, j = idx & 63;
        er[tt][j] = embed[x[b * SEQL + t0 + tt] * EMB + j];
    }
    __syncthreads();
    int i = tid;
    float base = bih0[i] + bhh0[i];
    float acc[8];
#pragma unroll
    for (int tt = 0; tt < 8; ++tt) acc[tt] = base;
    const float* wr = Wih0 + i * EMB;
    for (int j = 0; j < EMB; j += 4) {
        float4 w = *(const float4*)&wr[j];
#pragma unroll
        for (int tt = 0; tt < 8; ++tt) {
            float4 h = *(const float4*)&er[tt][j];
            acc[tt] += h.x * w.x + h.y * w.y + h.z * w.z + h.w * w.w;
        }
    }
#pragma unroll
    for (int tt = 0; tt < 8; ++tt)
        C0[((t0 + tt) * BATCH + b) * HID + i] = acc[tt];
}

// Persistent-weight recurrence (R3-verified form): h_t = tanh(C[t] + W*h_{t-1}).
// One WG per batch, 8 waves, wave w owns output cols [w*32, w*32+32).
// 1-step C prefetch; final prefetch over-reads one step into the next ws buffer
// (value discarded, memory valid).
__global__ __launch_bounds__(512) void rec_kernel(
    const float* __restrict__ W,     // [HID][HID], out[n] = sum_k h[k]*W[n][k]
    const float* __restrict__ C,     // [t][b][i]
    float* __restrict__ Hout)        // [b][t][i]
{
    int b = blockIdx.x;
    int tid = threadIdx.x;
    int wave = tid >> 6, lane = tid & 63;
    int lrow = lane & 15, lkg = lane >> 4;
    __shared__ f16 hbuf[2][HID];
    for (int idx = tid; idx < 2 * HID; idx += 512) ((f16*)hbuf)[idx] = (f16)0.f;

    // B-frag (verified layout): lane holds B[k=kt*32+lkg*8+e][n=wave*32+ct*16+lrow] = W[n][k]
    f16x8 bf[8][2];
#pragma unroll
    for (int kt = 0; kt < 8; ++kt)
#pragma unroll
        for (int ct = 0; ct < 2; ++ct) {
            int n = wave * 32 + ct * 16 + lrow;
            const float* src = W + n * HID + kt * 32 + lkg * 8;
            f16x8 v;
#pragma unroll
            for (int e = 0; e < 8; ++e) v[e] = (f16)src[e];
            bf[kt][ct] = v;
        }
    __syncthreads();

    int i0 = wave * 32 + lrow, i1 = i0 + 16;
    const float* cp = C + b * HID;
    float c0 = cp[i0], c1 = cp[i1];
    cp += BATCH * HID;
    float* ho = Hout + (size_t)b * TT * HID;

    // Persistent A-fragments: zero once; masked ds_read touches only lrow==0 lanes.
    f16x8 a[8];
#pragma unroll
    for (int kt = 0; kt < 8; ++kt)
#pragma unroll
        for (int e = 0; e < 8; ++e) a[kt][e] = (f16)0.f;
    const f32x4 Z = {0.f, 0.f, 0.f, 0.f};

#define RSTEP(CUR, NXT)                                                             \
    {                                                                               \
        float cn0 = cp[i0];                                                         \
        float cn1 = cp[i1];                                                         \
        cp += BATCH * HID;                                                          \
        if (lrow == 0) {                                                            \
            _Pragma("unroll")                                                       \
            for (int kt = 0; kt < 8; ++kt)                                          \
                a[kt] = *(const f16x8*)&hbuf[CUR][kt * 32 + lkg * 8];               \
        }                                                                           \
        f32x4 p00 = __builtin_amdgcn_mfma_f32_16x16x32_f16(a[0], bf[0][0], Z, 0, 0, 0); \
        f32x4 p01 = __builtin_amdgcn_mfma_f32_16x16x32_f16(a[0], bf[0][1], Z, 0, 0, 0); \
        f32x4 p10 = __builtin_amdgcn_mfma_f32_16x16x32_f16(a[2], bf[2][0], Z, 0, 0, 0); \
        f32x4 p11 = __builtin_amdgcn_mfma_f32_16x16x32_f16(a[2], bf[2][1], Z, 0, 0, 0); \
        f32x4 p20 = __builtin_amdgcn_mfma_f32_16x16x32_f16(a[4], bf[4][0], Z, 0, 0, 0); \
        f32x4 p21 = __builtin_amdgcn_mfma_f32_16x16x32_f16(a[4], bf[4][1], Z, 0, 0, 0); \
        f32x4 p30 = __builtin_amdgcn_mfma_f32_16x16x32_f16(a[6], bf[6][0], Z, 0, 0, 0); \
        f32x4 p31 = __builtin_amdgcn_mfma_f32_16x16x32_f16(a[6], bf[6][1], Z, 0, 0, 0); \
        p00 = __builtin_amdgcn_mfma_f32_16x16x32_f16(a[1], bf[1][0], p00, 0, 0, 0); \
        p01 = __builtin_amdgcn_mfma_f32_16x16x32_f16(a[1], bf[1][1], p01, 0, 0, 0); \
        p10 = __builtin_amdgcn_mfma_f32_16x16x32_f16(a[3], bf[3][0], p10, 0, 0, 0); \
        p11 = __builtin_amdgcn_mfma_f32_16x16x32_f16(a[3], bf[3][1], p11, 0, 0, 0); \
        p20 = __builtin_amdgcn_mfma_f32_16x16x32_f16(a[5], bf[5][0], p20, 0, 0, 0); \
        p21 = __builtin_amdgcn_mfma_f32_16x16x32_f16(a[5], bf[5][1], p21, 0, 0, 0); \
        p30 = __builtin_amdgcn_mfma_f32_16x16x32_f16(a[7], bf[7][0], p30, 0, 0, 0); \
        p31 = __builtin_amdgcn_mfma_f32_16x16x32_f16(a[7], bf[7][1], p31, 0, 0, 0); \
        float v0 = fast_tanh(((p00[0] + p10[0]) + (p20[0] + p30[0])) + c0);         \
        float v1 = fast_tanh(((p01[0] + p11[0]) + (p21[0] + p31[0])) + c1);         \
        if (lane < 16) {                                                            \
            hbuf[NXT][i0] = (f16)v0;                                                \
            hbuf[NXT][i1] = (f16)v1;                                                \
            ho[i0] = v0;                                                            \
            ho[i1] = v1;                                                            \
        }                                                                           \
        ho += HID;                                                                  \
        c0 = cn0; c1 = cn1;                                                         \
        asm volatile("s_waitcnt lgkmcnt(0)\n\ts_barrier" ::: "memory");             \
    }

    for (int t = 0; t < TT; t += 2) {
        RSTEP(0, 1)
        RSTEP(1, 0)
    }
#undef RSTEP
}

// Out[...] = In[b][t][:] . W[i][:] (+bias0[i]+bias1[i]); K = 256
__global__ __launch_bounds__(256) void gemm256_kernel(
    const float* __restrict__ In, const float* __restrict__ W,
    const float* __restrict__ bias0, const float* __restrict__ bias1,
    float* __restrict__ Out, int tmajor)
{
    int b  = blockIdx.x & 7;
    int t0 = (blockIdx.x >> 3) * 8;
    int tid = threadIdx.x;
    __shared__ float hs[8][HID];
    for (int idx = tid; idx < 8 * HID; idx += 256) {
        int tt = idx >> 8, j = idx & 255;
        hs[tt][j] = In[((size_t)b * TT + t0 + tt) * HID + j];
    }
    __syncthreads();
    int i = tid;
    float base = 0.f;
    if (bias0) base += bias0[i];
    if (bias1) base += bias1[i];
    float acc[8];
#pragma unroll
    for (int tt = 0; tt < 8; ++tt) acc[tt] = base;
    const float* wr = W + i * HID;
    for (int j = 0; j < HID; j += 4) {
        float4 w = *(const float4*)&wr[j];
#pragma unroll
        for (int tt = 0; tt < 8; ++tt) {
            float4 h = *(const float4*)&hs[tt][j];
            acc[tt] += h.x * w.x + h.y * w.y + h.z * w.z + h.w * w.w;
        }
    }
#pragma unroll
    for (int tt = 0; tt < 8; ++tt) {
        int t = t0 + tt;
        size_t o = tmajor ? ((size_t)(t * BATCH + b) * HID + i)
                          : (((size_t)b * TT + t) * HID + i);
        Out[o] = acc[tt];
    }
}

// tq[b][t][i] = tanh(Hs@Wq^T), tkT[b][i][t] = tanh(Hs@Wk^T) (transposed for coalesced attn reads)
__global__ __launch_bounds__(256) void gemmqk_kernel(
    const float* __restrict__ In, const float* __restrict__ Wq,
    const float* __restrict__ Wk, float* __restrict__ Oq, float* __restrict__ OkT)
{
    int b  = blockIdx.x & 7;
    int t0 = (blockIdx.x >> 3) * 8;
    int tid = threadIdx.x;
    __shared__ float hs[8][HID];
    for (int idx = tid; idx < 8 * HID; idx += 256) {
        int tt = idx >> 8, j = idx & 255;
        hs[tt][j] = In[((size_t)b * TT + t0 + tt) * HID + j];
    }
    __syncthreads();
    int i = tid;
    float aq[8], ak[8];
#pragma unroll
    for (int tt = 0; tt < 8; ++tt) { aq[tt] = 0.f; ak[tt] = 0.f; }
    const float* wq = Wq + i * HID;
    const float* wk = Wk + i * HID;
    for (int j = 0; j < HID; j += 4) {
        float4 q = *(const float4*)&wq[j];
        float4 k = *(const float4*)&wk[j];
#pragma unroll
        for (int tt = 0; tt < 8; ++tt) {
            float4 h = *(const float4*)&hs[tt][j];
            aq[tt] += h.x * q.x + h.y * q.y + h.z * q.z + h.w * q.w;
            ak[tt] += h.x * k.x + h.y * k.y + h.z * k.z + h.w * k.w;
        }
    }
#pragma unroll
    for (int tt = 0; tt < 8; ++tt)
        Oq[((size_t)b * TT + t0 + tt) * HID + i] = fast_tanh(aq[tt]);
    float4 kv0 = { fast_tanh(ak[0]), fast_tanh(ak[1]), fast_tanh(ak[2]), fast_tanh(ak[3]) };
    float4 kv1 = { fast_tanh(ak[4]), fast_tanh(ak[5]), fast_tanh(ak[6]), fast_tanh(ak[7]) };
    float* ko = OkT + ((size_t)b * HID + i) * TT + t0;
    *(float4*)&ko[0] = kv0;
    *(float4*)&ko[4] = kv1;
}

// Per (b, t-tile of TG): scores via tanh addition identity on precomputed tq,tk.
// b = blockIdx&7 -> batch pinned to one XCD (matches producers' L2).
// cvec is [TG][8][68]: part-stride 68 dwords breaks the p*64 bank aliasing in the FC reads.
__global__ __launch_bounds__(256) void attn_kernel(
    const float* __restrict__ tq, const float* __restrict__ tkT,
    const float* __restrict__ vvec, const float* __restrict__ Hs,
    const float* __restrict__ Wfc, const float* __restrict__ bfc,
    float* __restrict__ out)
{
    int b  = blockIdx.x & 7;
    int t0 = (blockIdx.x >> 3) * TG;
    int tid = threadIdx.x;
    int wave = tid >> 6, lane = tid & 63;
    __shared__ float qs[TG][HID], vs[HID], alpha[TG][HID];
    __shared__ float cvec[TG][8][68];
    __shared__ float redm[4][TG], reds[4][TG];
#pragma unroll
    for (int j = 0; j < TG; ++j)
        qs[j][tid] = tq[((size_t)b * TT + t0 + j) * HID + tid];
    vs[tid] = vvec[tid];
    __syncthreads();

    float sc[TG];
#pragma unroll
    for (int j = 0; j < TG; ++j) sc[j] = -1e30f;
    if ((wave << 6) < t0 + TG) {   // causality: whole-wave skip for s >= t0+TG
        const float* kT = tkT + (size_t)b * HID * TT + tid;
        float a0 = 0.f, a1 = 0.f, a2 = 0.f, a3 = 0.f;
        for (int jj = 0; jj < HID; jj += 4) {
            float k0 = kT[(size_t)(jj + 0) * TT];
            float k1 = kT[(size_t)(jj + 1) * TT];
            float k2 = kT[(size_t)(jj + 2) * TT];
            float k3 = kT[(size_t)(jj + 3) * TT];
            float4 vv = *(const float4*)&vs[jj];
            float4 q0 = *(const float4*)&qs[0][jj];
            float4 q1 = *(const float4*)&qs[1][jj];
            float4 q2 = *(const float4*)&qs[2][jj];
            float4 q3 = *(const float4*)&qs[3][jj];
#define TADD(qc, kc, vc, acc) { float num = qc + kc; float den = __builtin_fmaf(qc, kc, 1.f); acc += vc * num * __builtin_amdgcn_rcpf(den); }
            TADD(q0.x, k0, vv.x, a0) TADD(q0.y, k1, vv.y, a0) TADD(q0.z, k2, vv.z, a0) TADD(q0.w, k3, vv.w, a0)
            TADD(q1.x, k0, vv.x, a1) TADD(q1.y, k1, vv.y, a1) TADD(q1.z, k2, vv.z, a1) TADD(q1.w, k3, vv.w, a1)
            TADD(q2.x, k0, vv.x, a2) TADD(q2.y, k1, vv.y, a2) TADD(q2.z, k2, vv.z, a2) TADD(q2.w, k3, vv.w, a2)
            TADD(q3.x, k0, vv.x, a3) TADD(q3.y, k1, vv.y, a3) TADD(q3.z, k2, vv.z, a3) TADD(q3.w, k3, vv.w, a3)
#undef TADD
        }
        if (tid < t0 + 0) sc[0] = a0;
        if (tid < t0 + 1) sc[1] = a1;
        if (tid < t0 + 2) sc[2] = a2;
        if (tid < t0 + 3) sc[3] = a3;
    }
    float m0 = sc[0], m1 = sc[1], m2 = sc[2], m3 = sc[3];
#pragma unroll
    for (int off = 32; off; off >>= 1) {
        m0 = fmaxf(m0, __shfl_down(m0, off));
        m1 = fmaxf(m1, __shfl_down(m1, off));
        m2 = fmaxf(m2, __shfl_down(m2, off));
        m3 = fmaxf(m3, __shfl_down(m3, off));
    }
    if (lane == 0) { redm[wave][0] = m0; redm[wave][1] = m1; redm[wave][2] = m2; redm[wave][3] = m3; }
    __syncthreads();
    float ej[TG];
#pragma unroll
    for (int j = 0; j < TG; ++j) {
        float m = fmaxf(fmaxf(redm[0][j], redm[1][j]), fmaxf(redm[2][j], redm[3][j]));
        ej[j] = (tid < t0 + j) ? exp2f((sc[j] - m) * 1.4426950408889634f) : 0.f;
    }
    float z0 = ej[0], z1 = ej[1], z2 = ej[2], z3 = ej[3];
#pragma unroll
    for (int off = 32; off; off >>= 1) {
        z0 += __shfl_down(z0, off);
        z1 += __shfl_down(z1, off);
        z2 += __shfl_down(z2, off);
        z3 += __shfl_down(z3, off);
    }
    if (lane == 0) { reds[wave][0] = z0; reds[wave][1] = z1; reds[wave][2] = z2; reds[wave][3] = z3; }
    __syncthreads();
#pragma unroll
    for (int j = 0; j < TG; ++j) {
        float z = reds[0][j] + reds[1][j] + reds[2][j] + reds[3][j];
        alpha[j][tid] = (t0 + j == 0) ? 0.f : ej[j] * __builtin_amdgcn_rcpf(z);
    }
    __syncthreads();

    float c0 = 0.f, c1 = 0.f, c2 = 0.f, c3 = 0.f;
    const float* hb = Hs + (size_t)b * TT * HID;
    for (int s = 0; s < t0 + TG; s += 4) {
        float4 av0 = *(const float4*)&alpha[0][s];
        float4 av1 = *(const float4*)&alpha[1][s];
        float4 av2 = *(const float4*)&alpha[2][s];
        float4 av3 = *(const float4*)&alpha[3][s];
        float h0 = hb[(s + 0) * HID + tid];
        float h1 = hb[(s + 1) * HID + tid];
        float h2 = hb[(s + 2) * HID + tid];
        float h3 = hb[(s + 3) * HID + tid];
        c0 += av0.x * h0 + av0.y * h1 + av0.z * h2 + av0.w * h3;
        c1 += av1.x * h0 + av1.y * h1 + av1.z * h2 + av1.w * h3;
        c2 += av2.x * h0 + av2.y * h1 + av2.z * h2 + av2.w * h3;
        c3 += av3.x * h0 + av3.y * h1 + av3.z * h2 + av3.w * h3;
    }
    {
        int ph = tid >> 6, jj = tid & 63;
        cvec[0][ph][jj] = hb[(size_t)(t0 + 0) * HID + tid]; cvec[0][4 + ph][jj] = c0;
        cvec[1][ph][jj] = hb[(size_t)(t0 + 1) * HID + tid]; cvec[1][4 + ph][jj] = c1;
        cvec[2][ph][jj] = hb[(size_t)(t0 + 2) * HID + tid]; cvec[2][4 + ph][jj] = c2;
        cvec[3][ph][jj] = hb[(size_t)(t0 + 3) * HID + tid]; cvec[3][4 + ph][jj] = c3;
    }
    __syncthreads();

    if (tid < VOCAB * 8) {
        int o = tid >> 3, p = tid & 7;
        const float* wr = Wfc + o * 2 * HID + p * 64;
#pragma unroll
        for (int j = 0; j < TG; ++j) {
            const float* cv = &cvec[j][p][0];
            float a = 0.f;
            for (int jj = 0; jj < 64; jj += 4) {
                float4 w  = *(const float4*)&wr[jj];
                float4 cc = *(const float4*)&cv[jj];
                a += w.x * cc.x + w.y * cc.y + w.z * cc.z + w.w * cc.w;
            }
            a += __shfl_down(a, 4);
            a += __shfl_down(a, 2);
            a += __shfl_down(a, 1);
            if (p == 0) out[((size_t)b * TT + t0 + j) * VOCAB + o] = a + bfc[o];
        }
    }
}

extern "C" void kernel_launch(void* const* d_in, const int* in_sizes, int n_in,
                              void* d_out, int out_size, void* d_ws, size_t ws_size,
                              hipStream_t stream)
{
    (void)in_sizes; (void)n_in; (void)out_size; (void)ws_size;
    const int*   x     = (const int*)d_in[0];
    const float* embed = (const float*)d_in[1];
    const float* Wih0  = (const float*)d_in[2];
    const float* bih0  = (const float*)d_in[3];
    const float* Whh0  = (const float*)d_in[4];
    const float* bhh0  = (const float*)d_in[5];
    const float* Wih1  = (const float*)d_in[6];
    const float* bih1  = (const float*)d_in[7];
    const float* Whh1  = (const float*)d_in[8];
    const float* bhh1  = (const float*)d_in[9];
    const float* Wq    = (const float*)d_in[10];
    const float* Wk    = (const float*)d_in[11];
    const float* vvec  = (const float*)d_in[12];
    const float* Wfc   = (const float*)d_in[13];
    const float* bfc   = (const float*)d_in[14];
    float* out = (float*)d_out;
    float* ws  = (float*)d_ws;

    const size_t SZ = (size_t)TT * BATCH * HID;  // 524288 floats = 2 MB
    float* C0  = ws;           // reused as C1
    float* H0  = ws + SZ;      // h0 history, reused as tq
    float* Hs  = ws + 2 * SZ;
    float* tkT = ws + 3 * SZ;

    pre0_kernel<<<256, 256, 0, stream>>>(x, embed, Wih0, bih0, bhh0, C0);
    rec_kernel<<<8, 512, 0, stream>>>(Whh0, C0, H0);
    gemm256_kernel<<<256, 256, 0, stream>>>(H0, Wih1, bih1, bhh1, C0, 1);
    rec_kernel<<<8, 512, 0, stream>>>(Whh1, C0, Hs);
    gemmqk_kernel<<<256, 256, 0, stream>>>(Hs, Wq, Wk, H0, tkT);
    attn_kernel<<<512, 256, 0, stream>>>(H0, tkT, vvec, Hs, Wfc, bfc, out);
}